// Round 5
// baseline (72.702 us; speedup 1.0000x reference)
//
#include <hip/hip_runtime.h>

// Problem constants (B=4, S=4096, DM=1024, H=16, HD=64)
#define M_TOTAL 16384
#define DMODEL  1024
#define HDIM    64
#define NHEAD   16

typedef _Float16 half8 __attribute__((ext_vector_type(8)));
typedef float    f32x4 __attribute__((ext_vector_type(4)));

// ---------------------------------------------------------------------------
// Math note: scores[b,s,h,g] = q.k is constant over g (k is broadcast over the
// head axis) -> softmax exactly uniform -> out rows = v -> final =
// (x@Wv+bv) @ (sum_h Wo[h*64+d][n]) + bo.  Wq/bq/Wk/bk are mathematically dead.
//
// Prep: WvT[d][k] = Wv[k][d]  (f16)          [64][1024]
//       WosumT[n][d] = sum_h Wo[h*64+d][n]   [1024][64] (f16)
//       Vg zeroed (atomic accumulator for kernel A; re-zeroed every call).
// ---------------------------------------------------------------------------
__global__ __launch_bounds__(256) void prep_kernel(const float* __restrict__ Wv,
                                                   const float* __restrict__ Wo,
                                                   _Float16* __restrict__ WvT,
                                                   _Float16* __restrict__ WosumT,
                                                   float* __restrict__ Vg) {
    const int t = blockIdx.x * 256 + threadIdx.x;   // 0..65535
    {   // WvT: consecutive t -> consecutive d -> coalesced Wv reads
        const int d = t & 63, k = t >> 6;
        WvT[d * DMODEL + k] = (_Float16)Wv[k * HDIM + d];
    }
    {   // WosumT: consecutive t -> consecutive n -> coalesced Wo reads
        const int n = t & 1023, d = t >> 10;
        float s = 0.f;
        #pragma unroll
        for (int h = 0; h < NHEAD; ++h) s += Wo[(h * HDIM + d) * DMODEL + n];
        WosumT[n * HDIM + d] = (_Float16)s;
    }
    {   // zero Vg: 16 floats/thread
        f32x4 z = {};
        float* p = Vg + (size_t)t * 16;
        *(f32x4*)(p) = z; *(f32x4*)(p + 4) = z;
        *(f32x4*)(p + 8) = z; *(f32x4*)(p + 12) = z;
    }
}

// ---------------------------------------------------------------------------
// Kernel A: Vg[16384][64] (f32) += X @ Wv   (cross-block K-split x2, atomic).
// Grid 2048: block b -> tile t=b>>1 (16 rows), K-half kh=b&1.
// Wave w handles K in [kh*512 + w*128, +128): 8 float4 X loads, 16 MFMA.
// Block LDS-reduces its 4 wave-partials, atomicAdds 16x64 f32 (2 writers/elem;
// f32 add-order variance ~1e-7, far below the 0.048 threshold).
// 8192 waves total = 32 waves/CU (launch_bounds(256,8), LDS 17.4KB).
// MFMA 16x16x32 f16: A lane l: A[l&15][(l>>4)*8+j]; B lane l: B[(l>>4)*8+j][l&15];
// C lane l reg j: row (l>>4)*4+j, col l&15.
// ---------------------------------------------------------------------------
#define VP_S 68

__global__ __launch_bounds__(256, 8) void vproj_kernel(const float* __restrict__ X,
                                                       const _Float16* __restrict__ WvT,
                                                       float* __restrict__ Vg) {
    __shared__ float Vp[4][16][VP_S];   // 17408 B

    const int tid = threadIdx.x;
    const int l   = tid & 63;
    const int w   = tid >> 6;
    const int lr  = l & 15;
    const int lk  = l >> 4;
    const int m0  = (blockIdx.x >> 1) * 16;
    const int ks0 = (blockIdx.x & 1) * 512 + w * 128;

    const float* xp = X + (size_t)(m0 + lr) * DMODEL + ks0 + lk * 8;
    f32x4 xb[8];
    #pragma unroll
    for (int s = 0; s < 4; ++s) {
        xb[2 * s]     = *(const f32x4*)(xp + s * 32);
        xb[2 * s + 1] = *(const f32x4*)(xp + s * 32 + 4);
    }
    f32x4 acc[4] = {};
    #pragma unroll
    for (int s = 0; s < 4; ++s) {
        union { _Float16 h[8]; half8 v; } pk;
        #pragma unroll
        for (int j = 0; j < 4; ++j) {
            pk.h[j]     = (_Float16)xb[2 * s][j];
            pk.h[4 + j] = (_Float16)xb[2 * s + 1][j];
        }
        #pragma unroll
        for (int n4 = 0; n4 < 4; ++n4) {
            const half8 b = *(const half8*)&WvT[(size_t)(n4 * 16 + lr) * DMODEL + ks0 + s * 32 + lk * 8];
            acc[n4] = __builtin_amdgcn_mfma_f32_16x16x32_f16(pk.v, b, acc[n4], 0, 0, 0);
        }
    }
    #pragma unroll
    for (int n4 = 0; n4 < 4; ++n4)
        #pragma unroll
        for (int j = 0; j < 4; ++j)
            Vp[w][lk * 4 + j][n4 * 16 + lr] = acc[n4][j];
    __syncthreads();

    // reduce 4 wave-partials; thread owns 4 consecutive elems of the 16x64 tile
    const int idx = tid * 4;
    const int r   = idx >> 6;
    const int c   = idx & 63;
    f32x4 s4 = {};
    #pragma unroll
    for (int p = 0; p < 4; ++p) s4 += *(const f32x4*)&Vp[p][r][c];
    float* vg = &Vg[(size_t)(m0 + r) * HDIM + c];
    atomicAdd(vg + 0, s4[0]); atomicAdd(vg + 1, s4[1]);
    atomicAdd(vg + 2, s4[2]); atomicAdd(vg + 3, s4[3]);
}

// ---------------------------------------------------------------------------
// Kernel B: Out[16384][1024] (f32) = (Vg + bv) @ Wosum + bo.
// Grid 2048: block b -> tile t=b>>1, col-half ch=b&1; wave w owns 128 cols.
// Barrier-free, no LDS; Vg (4MB) is L2/L3-hot, WosumT (128KB) L2-resident.
// 8192 waves = 32 waves/CU.
// ---------------------------------------------------------------------------
__global__ __launch_bounds__(256, 8) void oproj_kernel(const float* __restrict__ Vg,
                                                       const float* __restrict__ bv,
                                                       const float* __restrict__ bo,
                                                       const _Float16* __restrict__ WosumT,
                                                       float* __restrict__ Out) {
    const int tid = threadIdx.x;
    const int l   = tid & 63;
    const int w   = tid >> 6;
    const int lr  = l & 15;
    const int lk  = l >> 4;
    const int m0  = (blockIdx.x >> 1) * 16;
    const int nb  = (blockIdx.x & 1) * 512 + w * 128;

    const float* vp = Vg + (size_t)(m0 + lr) * HDIM + lk * 8;
    const f32x4 v0 = *(const f32x4*)(vp);
    const f32x4 v1 = *(const f32x4*)(vp + 4);
    const f32x4 v2 = *(const f32x4*)(vp + 32);
    const f32x4 v3 = *(const f32x4*)(vp + 36);
    const f32x4 b0 = *(const f32x4*)&bv[lk * 8];
    const f32x4 b1 = *(const f32x4*)&bv[lk * 8 + 4];
    const f32x4 b2 = *(const f32x4*)&bv[32 + lk * 8];
    const f32x4 b3 = *(const f32x4*)&bv[32 + lk * 8 + 4];

    union { _Float16 h[8]; half8 v; } A0, A1;
    #pragma unroll
    for (int j = 0; j < 4; ++j) {
        A0.h[j]     = (_Float16)(v0[j] + b0[j]);
        A0.h[4 + j] = (_Float16)(v1[j] + b1[j]);
        A1.h[j]     = (_Float16)(v2[j] + b2[j]);
        A1.h[4 + j] = (_Float16)(v3[j] + b3[j]);
    }

    #pragma unroll 4
    for (int g = 0; g < 8; ++g) {
        const int n0 = nb + g * 16;
        const half8 w0 = *(const half8*)&WosumT[(size_t)(n0 + lr) * HDIM + lk * 8];
        const half8 w1 = *(const half8*)&WosumT[(size_t)(n0 + lr) * HDIM + 32 + lk * 8];
        f32x4 o = {};
        o = __builtin_amdgcn_mfma_f32_16x16x32_f16(A0.v, w0, o, 0, 0, 0);
        o = __builtin_amdgcn_mfma_f32_16x16x32_f16(A1.v, w1, o, 0, 0, 0);
        const float bov = bo[n0 + lr];
        #pragma unroll
        for (int j = 0; j < 4; ++j)
            Out[(size_t)(m0 + lk * 4 + j) * DMODEL + n0 + lr] = o[j] + bov;
    }
}

// ---------------------------------------------------------------------------
extern "C" void kernel_launch(void* const* d_in, const int* in_sizes, int n_in,
                              void* d_out, int out_size, void* d_ws, size_t ws_size,
                              hipStream_t stream) {
    const float* x  = (const float*)d_in[0];
    // d_in[1]=Wq, d_in[2]=bq, d_in[3]=Wk, d_in[4]=bk: mathematically dead.
    const float* Wv = (const float*)d_in[5];
    const float* bv = (const float*)d_in[6];
    const float* Wo = (const float*)d_in[7];
    const float* bo = (const float*)d_in[8];

    _Float16* WvT    = (_Float16*)d_ws;                            // 128 KB
    _Float16* WosumT = (_Float16*)((char*)d_ws + 64 * 1024 * 2);   // 128 KB
    float*    Vg     = (float*)((char*)d_ws + 256 * 1024);         // 4 MB f32
    float*    out    = (float*)d_out;

    prep_kernel<<<256, 256, 0, stream>>>(Wv, Wo, WvT, WosumT, Vg);
    vproj_kernel<<<2048, 256, 0, stream>>>(x, WvT, Vg);
    oproj_kernel<<<2048, 256, 0, stream>>>(Vg, bv, bo, WosumT, out);
}

// Round 6
// 61.640 us; speedup vs baseline: 1.1795x; 1.1795x over previous
//
#include <hip/hip_runtime.h>

// Problem constants (B=4, S=4096, DM=1024, H=16, HD=64)
#define M_TOTAL 16384
#define DMODEL  1024
#define HDIM    64
#define NHEAD   16

typedef _Float16 half8 __attribute__((ext_vector_type(8)));
typedef float    f32x4 __attribute__((ext_vector_type(4)));
typedef float    f32x2 __attribute__((ext_vector_type(2)));

// ---------------------------------------------------------------------------
// Math note: scores[b,s,h,g] = q.k is constant over g (k is broadcast over the
// head axis) -> softmax exactly uniform -> out rows = v -> final =
// (x@Wv+bv) @ (sum_h Wo[h*64+d][n]) + bo.  Wq/bq/Wk/bk are mathematically dead.
//
// Prep: WvT[d][k] = Wv[k][d]  (f16)          [64][1024]
//       WosumT[n][d] = sum_h Wo[h*64+d][n]   [1024][64] (f16)
// ---------------------------------------------------------------------------
__global__ __launch_bounds__(256) void prep_kernel(const float* __restrict__ Wv,
                                                   const float* __restrict__ Wo,
                                                   _Float16* __restrict__ WvT,
                                                   _Float16* __restrict__ WosumT) {
    const int t = blockIdx.x * 256 + threadIdx.x;   // 0..65535
    {   // WvT: consecutive t -> consecutive d -> coalesced Wv reads
        const int d = t & 63, k = t >> 6;
        WvT[d * DMODEL + k] = (_Float16)Wv[k * HDIM + d];
    }
    {   // WosumT: consecutive t -> consecutive n -> coalesced Wo reads
        const int n = t & 1023, d = t >> 10;
        float s = 0.f;
        #pragma unroll
        for (int h = 0; h < NHEAD; ++h) s += Wo[(h * HDIM + d) * DMODEL + n];
        WosumT[n * HDIM + d] = (_Float16)s;
    }
}

// ---------------------------------------------------------------------------
// Kernel A: V[16384][64] (f16) = X @ Wv + bv.
// 1024 blocks x 512 threads (8 waves). Wave w owns K in [w*128, w*128+128).
// Its ENTIRE WvT slice (16 half8 = 64 VGPRs) is preloaded before the K-loop,
// so the loop is pure {pack, 4 MFMA} with all 8 X loads issued up front --
// no per-iteration L2 fragment-load latency chain.
// 8 wave-partials reduced through LDS (+bv), written as f16. No atomics.
// MFMA 16x16x32 f16: A lane l: A[l&15][(l>>4)*8+j]; B lane l: B[(l>>4)*8+j][l&15];
// C lane l reg j: row (l>>4)*4+j, col l&15.
// ---------------------------------------------------------------------------
#define VP_S 68   // row stride in words

__global__ __launch_bounds__(512, 4) void vproj_kernel(const float* __restrict__ X,
                                                       const float* __restrict__ bv,
                                                       const _Float16* __restrict__ WvT,
                                                       _Float16* __restrict__ V) {
    __shared__ float Vp[8][16][VP_S];   // 34816 B

    const int tid = threadIdx.x;
    const int l   = tid & 63;
    const int w   = tid >> 6;           // 0..7
    const int lr  = l & 15;
    const int lk  = l >> 4;
    const int m0  = blockIdx.x * 16;
    const int k0  = w * 128;

    // X loads first (HBM latency), all 8 in flight
    const float* xp = X + (size_t)(m0 + lr) * DMODEL + k0 + lk * 8;
    f32x4 xb[8];
    #pragma unroll
    for (int s = 0; s < 4; ++s) {
        xb[2 * s]     = *(const f32x4*)(xp + s * 32);
        xb[2 * s + 1] = *(const f32x4*)(xp + s * 32 + 4);
    }
    // B-fragments: register-resident for the whole loop (16 x half8)
    half8 Bf[4][4];
    #pragma unroll
    for (int n4 = 0; n4 < 4; ++n4)
        #pragma unroll
        for (int s = 0; s < 4; ++s)
            Bf[n4][s] = *(const half8*)&WvT[(size_t)(n4 * 16 + lr) * DMODEL + k0 + s * 32 + lk * 8];

    f32x4 acc[4] = {};
    #pragma unroll
    for (int s = 0; s < 4; ++s) {
        union { _Float16 h[8]; half8 v; } pk;
        #pragma unroll
        for (int j = 0; j < 4; ++j) {
            pk.h[j]     = (_Float16)xb[2 * s][j];
            pk.h[4 + j] = (_Float16)xb[2 * s + 1][j];
        }
        #pragma unroll
        for (int n4 = 0; n4 < 4; ++n4)
            acc[n4] = __builtin_amdgcn_mfma_f32_16x16x32_f16(pk.v, Bf[n4][s], acc[n4], 0, 0, 0);
    }
    #pragma unroll
    for (int n4 = 0; n4 < 4; ++n4)
        #pragma unroll
        for (int j = 0; j < 4; ++j)
            Vp[w][lk * 4 + j][n4 * 16 + lr] = acc[n4][j];
    __syncthreads();

    // reduce 8 partials; thread owns 2 consecutive elems of the 16x64 tile
    const int idx = tid * 2;
    const int r   = idx >> 6;
    const int c   = idx & 63;
    f32x2 s2 = {};
    #pragma unroll
    for (int p = 0; p < 8; ++p) s2 += *(const f32x2*)&Vp[p][r][c];
    s2 += *(const f32x2*)&bv[c];
    union { _Float16 h[2]; unsigned int u; } o;
    o.h[0] = (_Float16)s2[0];
    o.h[1] = (_Float16)s2[1];
    *(unsigned int*)&V[(size_t)(m0 + r) * HDIM + c] = o.u;
}

// ---------------------------------------------------------------------------
// Kernel B: Out[16384][1024] (f32) = V @ Wosum + bo.   (V already includes bv.)
// 2048 blocks x 256 threads: block b -> tile b>>1 (16 rows), col-half b&1;
// wave w owns 128 cols. B-fragments double-buffered in registers (prefetch
// g+1 while MFMA g). Barrier-free, no LDS. 32 waves/CU.
// ---------------------------------------------------------------------------
__global__ __launch_bounds__(256, 8) void oproj_kernel(const _Float16* __restrict__ V,
                                                       const float* __restrict__ bo,
                                                       const _Float16* __restrict__ WosumT,
                                                       float* __restrict__ Out) {
    const int tid = threadIdx.x;
    const int l   = tid & 63;
    const int w   = tid >> 6;
    const int lr  = l & 15;
    const int lk  = l >> 4;
    const int m0  = (blockIdx.x >> 1) * 16;
    const int nb  = (blockIdx.x & 1) * 512 + w * 128;

    const _Float16* vp = V + (size_t)(m0 + lr) * HDIM + lk * 8;
    const half8 a0 = *(const half8*)vp;
    const half8 a1 = *(const half8*)(vp + 32);

    const _Float16* wb = &WosumT[(size_t)(nb + lr) * HDIM];
    half8 b0 = *(const half8*)(wb + lk * 8);
    half8 b1 = *(const half8*)(wb + 32 + lk * 8);

    #pragma unroll
    for (int g = 0; g < 8; ++g) {
        const half8 c0 = b0, c1 = b1;
        if (g < 7) {
            const _Float16* wn = wb + (size_t)(g + 1) * 16 * HDIM;
            b0 = *(const half8*)(wn + lk * 8);
            b1 = *(const half8*)(wn + 32 + lk * 8);
        }
        f32x4 o = {};
        o = __builtin_amdgcn_mfma_f32_16x16x32_f16(a0, c0, o, 0, 0, 0);
        o = __builtin_amdgcn_mfma_f32_16x16x32_f16(a1, c1, o, 0, 0, 0);
        const int n0 = nb + g * 16;
        const float bov = bo[n0 + lr];
        #pragma unroll
        for (int j = 0; j < 4; ++j)
            Out[(size_t)(m0 + lk * 4 + j) * DMODEL + n0 + lr] = o[j] + bov;
    }
}

// ---------------------------------------------------------------------------
extern "C" void kernel_launch(void* const* d_in, const int* in_sizes, int n_in,
                              void* d_out, int out_size, void* d_ws, size_t ws_size,
                              hipStream_t stream) {
    const float* x  = (const float*)d_in[0];
    // d_in[1]=Wq, d_in[2]=bq, d_in[3]=Wk, d_in[4]=bk: mathematically dead.
    const float* Wv = (const float*)d_in[5];
    const float* bv = (const float*)d_in[6];
    const float* Wo = (const float*)d_in[7];
    const float* bo = (const float*)d_in[8];

    _Float16* WvT    = (_Float16*)d_ws;                            // 128 KB
    _Float16* WosumT = (_Float16*)((char*)d_ws + 64 * 1024 * 2);   // 128 KB
    _Float16* V      = (_Float16*)((char*)d_ws + 256 * 1024);      // 2 MB f16
    float*    out    = (float*)d_out;

    prep_kernel<<<256, 256, 0, stream>>>(Wv, Wo, WvT, WosumT);
    vproj_kernel<<<M_TOTAL / 16, 512, 0, stream>>>(x, bv, WvT, V);
    oproj_kernel<<<2048, 256, 0, stream>>>(V, bo, WosumT, out);
}

// Round 7
// 55.756 us; speedup vs baseline: 1.3039x; 1.1055x over previous
//
#include <hip/hip_runtime.h>

// Problem constants (B=4, S=4096, DM=1024, H=16, HD=64)
#define M_TOTAL 16384
#define DMODEL  1024
#define HDIM    64
#define NHEAD   16

typedef _Float16 half8 __attribute__((ext_vector_type(8)));
typedef float    f32x4 __attribute__((ext_vector_type(4)));
typedef float    f32x2 __attribute__((ext_vector_type(2)));

// ---------------------------------------------------------------------------
// Math note: scores[b,s,h,g] = q.k is constant over g (k is broadcast over the
// head axis) -> softmax exactly uniform -> out rows = v -> final =
// (x@Wv+bv) @ (sum_h Wo[h*64+d][n]) + bo.  Wq/bq/Wk/bk are mathematically dead.
//
// Prep: WvT[d][k] = Wv[k][d]  (f16)          [64][1024]
//       WosumT[n][d] = sum_h Wo[h*64+d][n]   [1024][64] (f16)
// ---------------------------------------------------------------------------
__global__ __launch_bounds__(256) void prep_kernel(const float* __restrict__ Wv,
                                                   const float* __restrict__ Wo,
                                                   _Float16* __restrict__ WvT,
                                                   _Float16* __restrict__ WosumT) {
    const int t = blockIdx.x * 256 + threadIdx.x;   // 0..65535
    {   // WvT: consecutive t -> consecutive d -> coalesced Wv reads
        const int d = t & 63, k = t >> 6;
        WvT[d * DMODEL + k] = (_Float16)Wv[k * HDIM + d];
    }
    {   // WosumT: consecutive t -> consecutive n -> coalesced Wo reads
        const int n = t & 1023, d = t >> 10;
        float s = 0.f;
        #pragma unroll
        for (int h = 0; h < NHEAD; ++h) s += Wo[(h * HDIM + d) * DMODEL + n];
        WosumT[n * HDIM + d] = (_Float16)s;
    }
}

// ---------------------------------------------------------------------------
// Kernel A: V[16384][64] (f16) = X @ Wv + bv.   (proven ~14 us in round 6)
// 1024 blocks x 512 threads (8 waves). Wave w owns K in [w*128, w*128+128).
// Entire WvT slice (16 half8 = 64 VGPRs) preloaded; loop is pure {pack,4 MFMA}
// with all 8 X loads in flight. 8 partials LDS-reduced (+bv) -> f16.
// MFMA 16x16x32 f16: A lane l: A[l&15][(l>>4)*8+j]; B lane l: B[(l>>4)*8+j][l&15];
// C lane l reg j: row (l>>4)*4+j, col l&15.
// ---------------------------------------------------------------------------
#define VP_S 68   // row stride in words

__global__ __launch_bounds__(512, 4) void vproj_kernel(const float* __restrict__ X,
                                                       const float* __restrict__ bv,
                                                       const _Float16* __restrict__ WvT,
                                                       _Float16* __restrict__ V) {
    __shared__ float Vp[8][16][VP_S];   // 34816 B

    const int tid = threadIdx.x;
    const int l   = tid & 63;
    const int w   = tid >> 6;           // 0..7
    const int lr  = l & 15;
    const int lk  = l >> 4;
    const int m0  = blockIdx.x * 16;
    const int k0  = w * 128;

    // X loads first (HBM latency), all 8 in flight
    const float* xp = X + (size_t)(m0 + lr) * DMODEL + k0 + lk * 8;
    f32x4 xb[8];
    #pragma unroll
    for (int s = 0; s < 4; ++s) {
        xb[2 * s]     = *(const f32x4*)(xp + s * 32);
        xb[2 * s + 1] = *(const f32x4*)(xp + s * 32 + 4);
    }
    // B-fragments: register-resident for the whole loop (16 x half8)
    half8 Bf[4][4];
    #pragma unroll
    for (int n4 = 0; n4 < 4; ++n4)
        #pragma unroll
        for (int s = 0; s < 4; ++s)
            Bf[n4][s] = *(const half8*)&WvT[(size_t)(n4 * 16 + lr) * DMODEL + k0 + s * 32 + lk * 8];

    f32x4 acc[4] = {};
    #pragma unroll
    for (int s = 0; s < 4; ++s) {
        union { _Float16 h[8]; half8 v; } pk;
        #pragma unroll
        for (int j = 0; j < 4; ++j) {
            pk.h[j]     = (_Float16)xb[2 * s][j];
            pk.h[4 + j] = (_Float16)xb[2 * s + 1][j];
        }
        #pragma unroll
        for (int n4 = 0; n4 < 4; ++n4)
            acc[n4] = __builtin_amdgcn_mfma_f32_16x16x32_f16(pk.v, Bf[n4][s], acc[n4], 0, 0, 0);
    }
    #pragma unroll
    for (int n4 = 0; n4 < 4; ++n4)
        #pragma unroll
        for (int j = 0; j < 4; ++j)
            Vp[w][lk * 4 + j][n4 * 16 + lr] = acc[n4][j];
    __syncthreads();

    // reduce 8 partials; thread owns 2 consecutive elems of the 16x64 tile
    const int idx = tid * 2;
    const int r   = idx >> 6;
    const int c   = idx & 63;
    f32x2 s2 = {};
    #pragma unroll
    for (int p = 0; p < 8; ++p) s2 += *(const f32x2*)&Vp[p][r][c];
    s2 += *(const f32x2*)&bv[c];
    union { _Float16 h[2]; unsigned int u; } o;
    o.h[0] = (_Float16)s2[0];
    o.h[1] = (_Float16)s2[1];
    *(unsigned int*)&V[(size_t)(m0 + r) * HDIM + c] = o.u;
}

// ---------------------------------------------------------------------------
// Kernel B: Out[16384][1024] (f32) = V @ Wosum + bo.   (V already includes bv.)
// 1024 blocks x 256 thr, launch_bounds(256,4) -> 128-VGPR budget, 16 waves/CU.
// Wave w owns cols [w*256,+256) as 2 halves of 128. Per half: ALL 16 B-frags
// preloaded (64 VGPRs), 16 MFMA back-to-back, C(+bo) -> wave-private LDS,
// then 8 f32x4 stores/lane; each store instr writes 2 complete rows x 512B
// (every 128B line fully dirtied by ONE instruction -> no write amplification).
// ---------------------------------------------------------------------------
#define OB_S 132   // 128 + 4 pad (rows offset by 4 banks)

__global__ __launch_bounds__(256, 4) void oproj_kernel(const _Float16* __restrict__ V,
                                                       const float* __restrict__ bo,
                                                       const _Float16* __restrict__ WosumT,
                                                       float* __restrict__ Out) {
    __shared__ float Ob[4][16][OB_S];   // 33792 B

    const int tid = threadIdx.x;
    const int l   = tid & 63;
    const int w   = tid >> 6;
    const int lr  = l & 15;
    const int lk  = l >> 4;
    const int m0  = blockIdx.x * 16;

    const _Float16* vp = V + (size_t)(m0 + lr) * HDIM + lk * 8;
    const half8 a0 = *(const half8*)vp;
    const half8 a1 = *(const half8*)(vp + 32);

    const int rs = l >> 5;      // store row parity (0/1)
    const int ck = l & 31;      // store 16B-chunk index within 128 cols

    #pragma unroll
    for (int h = 0; h < 2; ++h) {
        const int cb = w * 256 + h * 128;   // col base of this half
        // preload all 16 B-frags (issued back-to-back; one vmcnt wait)
        half8 Bf[8][2];
        #pragma unroll
        for (int t = 0; t < 8; ++t) {
            const _Float16* wb = &WosumT[(size_t)(cb + t * 16 + lr) * HDIM];
            Bf[t][0] = *(const half8*)(wb + lk * 8);
            Bf[t][1] = *(const half8*)(wb + 32 + lk * 8);
        }
        #pragma unroll
        for (int t = 0; t < 8; ++t) {
            f32x4 o = {};
            o = __builtin_amdgcn_mfma_f32_16x16x32_f16(a0, Bf[t][0], o, 0, 0, 0);
            o = __builtin_amdgcn_mfma_f32_16x16x32_f16(a1, Bf[t][1], o, 0, 0, 0);
            const float bov = bo[cb + t * 16 + lr];
            #pragma unroll
            for (int j = 0; j < 4; ++j)
                Ob[w][lk * 4 + j][t * 16 + lr] = o[j] + bov;   // 2-way bank alias: free
        }
        // same-wave LDS RAW -> compiler-inserted lgkmcnt; no barrier needed.
        // store instr i: rows {2i, 2i+1}, each row 512B fully contiguous.
        #pragma unroll
        for (int i = 0; i < 8; ++i) {
            const int r = i * 2 + rs;
            const f32x4 v4 = *(const f32x4*)&Ob[w][r][ck * 4];
            *(f32x4*)&Out[(size_t)(m0 + r) * DMODEL + cb + ck * 4] = v4;
        }
    }
}

// ---------------------------------------------------------------------------
extern "C" void kernel_launch(void* const* d_in, const int* in_sizes, int n_in,
                              void* d_out, int out_size, void* d_ws, size_t ws_size,
                              hipStream_t stream) {
    const float* x  = (const float*)d_in[0];
    // d_in[1]=Wq, d_in[2]=bq, d_in[3]=Wk, d_in[4]=bk: mathematically dead.
    const float* Wv = (const float*)d_in[5];
    const float* bv = (const float*)d_in[6];
    const float* Wo = (const float*)d_in[7];
    const float* bo = (const float*)d_in[8];

    _Float16* WvT    = (_Float16*)d_ws;                            // 128 KB
    _Float16* WosumT = (_Float16*)((char*)d_ws + 64 * 1024 * 2);   // 128 KB
    _Float16* V      = (_Float16*)((char*)d_ws + 256 * 1024);      // 2 MB f16
    float*    out    = (float*)d_out;

    prep_kernel<<<256, 256, 0, stream>>>(Wv, Wo, WvT, WosumT);
    vproj_kernel<<<M_TOTAL / 16, 512, 0, stream>>>(x, bv, WvT, V);
    oproj_kernel<<<M_TOTAL / 16, 256, 0, stream>>>(V, bo, WosumT, out);
}